// Round 3
// baseline (207.183 us; speedup 1.0000x reference)
//
#include <hip/hip_runtime.h>
#include <math.h>

#define NBATCH 2
#define KBOX   512
#define CCH    256
#define NBIN   49                 // 7x7 bins
#define CPW    16                 // channels per wave
#define WAVES  4                  // waves per block (256 threads)
#define CPB    (CPW*WAVES)        // 64 channels per block
#define GPB    (CCH/CPB)          // 4 blocks per box
#define COUT   (CCH*NBIN)         // 12544 outputs per box

__global__ __launch_bounds__(256) void roi_align_kernel(
    const float* __restrict__ f2, const float* __restrict__ f3,
    const float* __restrict__ f4, const float* __restrict__ f5,
    const float* __restrict__ boxes, float* __restrict__ out)
{
    const int bid  = blockIdx.x;
    const int m    = bid >> 2;        // box index (GPB == 4)
    const int cg   = bid & 3;         // channel group within box
    const int tid  = threadIdx.x;
    const int lane = tid & 63;
    const int wid  = tid >> 6;
    const int b    = m / KBOX;        // batch index

    // ---- box, level selection ----
    const float x1 = boxes[m*4+0];
    const float y1 = boxes[m*4+1];
    const float x2 = boxes[m*4+2];
    const float y2 = boxes[m*4+3];

    const float area = (x2 - x1) * (y2 - y1);
    const float size = sqrtf(area);
    float lvlf = floorf(4.0f + log2f(size / 224.0f + 1e-8f));
    lvlf = fminf(fmaxf(lvlf, 2.0f), 5.0f);
    const int lvl = (int)lvlf - 2;    // 0..3

    const int   H     = 256 >> lvl;   // square feature maps
    const int   HH    = H * H;
    const float scale = 0.25f / (float)(1 << lvl);
    const float Hf    = (float)H;

    const float* fptr = (lvl == 0) ? f2 : (lvl == 1) ? f3 : (lvl == 2) ? f4 : f5;
    const int c0 = cg * CPB + wid * CPW;                       // this wave's first channel
    const float* plane0 = fptr + ((size_t)b * CCH + c0) * HH;  // first plane for this wave

    // aligned=True: subtract 0.5 after scaling
    const float bx1 = x1 * scale - 0.5f;
    const float by1 = y1 * scale - 0.5f;
    const float bin_w = (x2 * scale - 0.5f - bx1) / 7.0f;
    const float bin_h = (y2 * scale - 0.5f - by1) / 7.0f;

    // ---- per-lane bin table, entirely in registers ----
    const int bin = (lane < 49) ? lane : 48;   // lanes 49..63 duplicate bin 48 (store-masked)
    const int py  = bin / 7;
    const int px  = bin - py * 7;

    int   o[4][4];
    float w[4][4];
    #pragma unroll
    for (int s = 0; s < 4; ++s) {
        const int iy = s >> 1;
        const int ix = s & 1;
        const float gy = ((float)(2*py + iy) + 0.5f) * 0.5f;
        const float gx = ((float)(2*px + ix) + 0.5f) * 0.5f;
        const float yy = by1 + gy * bin_h;
        const float xx = bx1 + gx * bin_w;

        const bool valid = (yy >= -1.0f) && (yy <= Hf) && (xx >= -1.0f) && (xx <= Hf);

        const float yc = fmaxf(yy, 0.0f);
        const float xc = fmaxf(xx, 0.0f);
        int yl = min((int)floorf(yc), H - 1);
        int xl = min((int)floorf(xc), H - 1);
        const int yh = min(yl + 1, H - 1);
        const int xh = min(xl + 1, H - 1);
        const float fy = yc - (float)yl;
        const float fx = xc - (float)xl;

        const float vm = valid ? 0.25f : 0.0f;   // fold the 2x2-mean into the weights
        w[s][0] = (1.0f - fy) * (1.0f - fx) * vm;
        w[s][1] = (1.0f - fy) * fx          * vm;
        w[s][2] = fy          * (1.0f - fx) * vm;
        w[s][3] = fy          * fx          * vm;
        o[s][0] = yl * H + xl;
        o[s][1] = yl * H + xh;
        o[s][2] = yh * H + xl;
        o[s][3] = yh * H + xh;
    }

    // ---- channel loop: 16 gathers + 16 FMAs + 1 predicated store each ----
    float* outp = out + (size_t)m * COUT + (size_t)c0 * NBIN + lane;

    #pragma unroll 2
    for (int k = 0; k < CPW; ++k) {
        const float* pl = plane0 + (size_t)k * HH;
        float acc = 0.0f;
        #pragma unroll
        for (int s = 0; s < 4; ++s) {
            acc += w[s][0] * pl[o[s][0]];
            acc += w[s][1] * pl[o[s][1]];
            acc += w[s][2] * pl[o[s][2]];
            acc += w[s][3] * pl[o[s][3]];
        }
        if (lane < 49)
            __builtin_nontemporal_store(acc, outp + k * NBIN);
    }
}

extern "C" void kernel_launch(void* const* d_in, const int* in_sizes, int n_in,
                              void* d_out, int out_size, void* d_ws, size_t ws_size,
                              hipStream_t stream) {
    const float* f2    = (const float*)d_in[0];
    const float* f3    = (const float*)d_in[1];
    const float* f4    = (const float*)d_in[2];
    const float* f5    = (const float*)d_in[3];
    const float* boxes = (const float*)d_in[4];
    float* outp = (float*)d_out;

    dim3 grid(NBATCH * KBOX * GPB);   // 4096 blocks: 4 per box, 64 channels each
    dim3 block(256);
    roi_align_kernel<<<grid, block, 0, stream>>>(f2, f3, f4, f5, boxes, outp);
}

// Round 4
// 168.446 us; speedup vs baseline: 1.2300x; 1.2300x over previous
//
#include <hip/hip_runtime.h>
#include <math.h>

#define NBATCH 2
#define KBOX   512
#define CCH    256
#define NBIN   49                 // 7x7 bins
#define CPW    16                 // channels per wave
#define WAVES  4                  // waves per block (256 threads)
#define CPB    (CPW*WAVES)        // 64 channels per block
#define GPB    (CCH/CPB)          // 4 blocks per box
#define COUT   (CCH*NBIN)         // 12544 outputs per box

__global__ __launch_bounds__(256, 2) void roi_align_kernel(
    const float* __restrict__ f2, const float* __restrict__ f3,
    const float* __restrict__ f4, const float* __restrict__ f5,
    const float* __restrict__ boxes, float* __restrict__ out)
{
    const int bid  = blockIdx.x;
    const int m    = bid >> 2;        // box index (GPB == 4)
    const int cg   = bid & 3;         // channel group within box
    const int tid  = threadIdx.x;
    const int lane = tid & 63;
    const int wid  = tid >> 6;
    const int b    = m / KBOX;        // batch index

    // ---- box, level selection ----
    const float x1 = boxes[m*4+0];
    const float y1 = boxes[m*4+1];
    const float x2 = boxes[m*4+2];
    const float y2 = boxes[m*4+3];

    const float area = (x2 - x1) * (y2 - y1);
    const float size = sqrtf(area);
    float lvlf = floorf(4.0f + log2f(size / 224.0f + 1e-8f));
    lvlf = fminf(fmaxf(lvlf, 2.0f), 5.0f);
    const int lvl = (int)lvlf - 2;    // 0..3

    const int   H     = 256 >> lvl;   // square feature maps
    const int   HH    = H * H;
    const float scale = 0.25f / (float)(1 << lvl);
    const float Hf    = (float)H;

    const float* fptr = (lvl == 0) ? f2 : (lvl == 1) ? f3 : (lvl == 2) ? f4 : f5;
    const int c0 = cg * CPB + wid * CPW;                       // this wave's first channel
    const float* plane0 = fptr + ((size_t)b * CCH + c0) * HH;  // first plane for this wave

    // aligned=True: subtract 0.5 after scaling
    const float bx1 = x1 * scale - 0.5f;
    const float by1 = y1 * scale - 0.5f;
    const float bin_w = (x2 * scale - 0.5f - bx1) / 7.0f;
    const float bin_h = (y2 * scale - 0.5f - by1) / 7.0f;

    // ---- per-lane bin table, entirely in registers ----
    const int bin = (lane < 49) ? lane : 48;   // lanes 49..63 duplicate bin 48 (store-masked)
    const int py  = bin / 7;
    const int px  = bin - py * 7;

    int   o[16];
    float w[16];
    #pragma unroll
    for (int s = 0; s < 4; ++s) {
        const int iy = s >> 1;
        const int ix = s & 1;
        const float gy = ((float)(2*py + iy) + 0.5f) * 0.5f;
        const float gx = ((float)(2*px + ix) + 0.5f) * 0.5f;
        const float yy = by1 + gy * bin_h;
        const float xx = bx1 + gx * bin_w;

        const bool valid = (yy >= -1.0f) && (yy <= Hf) && (xx >= -1.0f) && (xx <= Hf);

        const float yc = fmaxf(yy, 0.0f);
        const float xc = fmaxf(xx, 0.0f);
        int yl = min((int)floorf(yc), H - 1);
        int xl = min((int)floorf(xc), H - 1);
        const int yh = min(yl + 1, H - 1);
        const int xh = min(xl + 1, H - 1);
        const float fy = yc - (float)yl;
        const float fx = xc - (float)xl;

        const float vm = valid ? 0.25f : 0.0f;   // fold the 2x2-mean into the weights
        w[s*4+0] = (1.0f - fy) * (1.0f - fx) * vm;
        w[s*4+1] = (1.0f - fy) * fx          * vm;
        w[s*4+2] = fy          * (1.0f - fx) * vm;
        w[s*4+3] = fy          * fx          * vm;
        o[s*4+0] = yl * H + xl;
        o[s*4+1] = yl * H + xh;
        o[s*4+2] = yh * H + xl;
        o[s*4+3] = yh * H + xh;
    }

    // ---- channel loop: 2 channels/iter, 32 loads in flight, then FMAs ----
    float* outp = out + (size_t)m * COUT + (size_t)c0 * NBIN + lane;
    const bool active = (lane < 49);

    #pragma unroll 1
    for (int k = 0; k < CPW; k += 2) {
        const float* p0 = plane0 + (size_t)k * HH;
        const float* p1 = p0 + HH;

        float v0[16], v1[16];
        #pragma unroll
        for (int t = 0; t < 16; ++t) v0[t] = p0[o[t]];
        #pragma unroll
        for (int t = 0; t < 16; ++t) v1[t] = p1[o[t]];

        float acc0 = 0.0f, acc1 = 0.0f;
        #pragma unroll
        for (int t = 0; t < 16; ++t) {
            acc0 += w[t] * v0[t];
            acc1 += w[t] * v1[t];
        }
        if (active) {
            __builtin_nontemporal_store(acc0, outp + (k    ) * NBIN);
            __builtin_nontemporal_store(acc1, outp + (k + 1) * NBIN);
        }
    }
}

extern "C" void kernel_launch(void* const* d_in, const int* in_sizes, int n_in,
                              void* d_out, int out_size, void* d_ws, size_t ws_size,
                              hipStream_t stream) {
    const float* f2    = (const float*)d_in[0];
    const float* f3    = (const float*)d_in[1];
    const float* f4    = (const float*)d_in[2];
    const float* f5    = (const float*)d_in[3];
    const float* boxes = (const float*)d_in[4];
    float* outp = (float*)d_out;

    dim3 grid(NBATCH * KBOX * GPB);   // 4096 blocks: 4 per box, 64 channels each
    dim3 block(256);
    roi_align_kernel<<<grid, block, 0, stream>>>(f2, f3, f4, f5, boxes, outp);
}